// Round 4
// baseline (114.761 us; speedup 1.0000x reference)
//
#include <hip/hip_runtime.h>
#include <math.h>

#define NHID 512
#define T_K  256
#define T_Q  128
#define BB   8

// tanh(x) = 1 - 2/(exp2(C*x)+1), C = 2*log2(e)
constexpr float C2L2E = 2.8853900817779268f;
constexpr float L2E   = 1.4426950408889634f;

__device__ __forceinline__ float fexp2(float x) { return __builtin_amdgcn_exp2f(x); }
__device__ __forceinline__ float frcp(float x)  { return __builtin_amdgcn_rcpf(x); }

typedef __attribute__((ext_vector_type(8))) short bf16x8;
typedef __attribute__((ext_vector_type(4))) float f32x4;
typedef __attribute__((ext_vector_type(2))) float f32x2;
typedef __attribute__((ext_vector_type(4))) float f32x4v;

__device__ __forceinline__ f32x2 fma2(f32x2 a, f32x2 b, f32x2 c) {
    return __builtin_elementwise_fma(a, b, c);
}

__device__ __forceinline__ unsigned short f2bf(float x) {
    unsigned u = __builtin_bit_cast(unsigned, x);
    unsigned r = (u + 0x7FFFu + ((u >> 16) & 1u)) >> 16;
    return (unsigned short)r;
}
__device__ __forceinline__ float bf2f(unsigned short h) {
    unsigned u = ((unsigned)h) << 16;
    return __builtin_bit_cast(float, u);
}
__device__ __forceinline__ unsigned packbf(float a, float b) {
    return (unsigned)f2bf(a) | ((unsigned)f2bf(b) << 16);
}
__device__ __forceinline__ float lo16(unsigned u) {
    return __builtin_bit_cast(float, u << 16);
}
__device__ __forceinline__ float hi16(unsigned u) {
    return __builtin_bit_cast(float, u & 0xFFFF0000u);
}

// ---------------------------------------------------------------------------
// Kernel 0 (NEW): prep — one-time f32 -> bf16 hi/lo conversion of A (ckey|qry)
// and W1 into pre-swizzled blobs that proj can stage with plain uint4 copies.
// Also emits ckp (hi-bf16 of ckey) for free. Removes ALL conversion VALU from
// proj's hot loop; W1's conversion (previously repeated by 96 row-blocks) is
// now done once. Bit-identical bf16 values vs the old in-proj conversion.
// Blobs:
//   ash/asl: [96 rowblk][8 kchunk][2048 ushort]  (32r x 64k swizzled tile, 4KB)
//   w1h/w1l: [128 tile=(h*8+c0)*8+kc][4096 ushort] (64n x 64k swizzled, 8KB)
// ---------------------------------------------------------------------------
__global__ __launch_bounds__(256) void prep_kernel(
    const float* __restrict__ qry, const float* __restrict__ ckey,
    const float* __restrict__ W1,
    unsigned short* __restrict__ ash, unsigned short* __restrict__ asl,
    unsigned short* __restrict__ w1h, unsigned short* __restrict__ w1l,
    unsigned int* __restrict__ ckp)
{
    const int t   = threadIdx.x;
    const int bid = blockIdx.x;
    if (bid < 96) {
        // ---- A rowblock: rows bid*32 .. +31, all 8 k-chunks ----
        const int rb = bid;
        const int r  = t >> 3;
        const int ca = t & 7;
        const int row = rb * 32 + r;
        const float* src = (row < 2048) ? (ckey + (size_t)row * 512)
                                        : (qry + (size_t)(row - 2048) * 512);
        const int swoff = r * 64 + ((ca ^ (r & 7)) * 8);
        unsigned short* dh = ash + (size_t)rb * 8 * 2048;
        unsigned short* dl = asl + (size_t)rb * 8 * 2048;
        unsigned int* ckpd = (row < 2048)
            ? ckp + ((size_t)(row & 7) * 256 + (row >> 3)) * 256
            : nullptr;
        #pragma unroll
        for (int kc = 0; kc < 8; ++kc) {
            const float4 f0 = *(const float4*)&src[kc * 64 + ca * 8];
            const float4 f1 = *(const float4*)&src[kc * 64 + ca * 8 + 4];
            float fa[8];
            *(float4*)&fa[0] = f0; *(float4*)&fa[4] = f1;
            union { uint4 v; unsigned short s[8]; } hv, lv;
            #pragma unroll
            for (int e = 0; e < 8; ++e) {
                const unsigned short hb = f2bf(fa[e]);
                hv.s[e] = hb; lv.s[e] = f2bf(fa[e] - bf2f(hb));
            }
            *(uint4*)&dh[kc * 2048 + swoff] = hv.v;
            *(uint4*)&dl[kc * 2048 + swoff] = lv.v;
            if (ckpd)
                *(uint4*)&ckpd[kc * 32 + ca * 4] = hv.v;
        }
    } else {
        // ---- W1 tile: tid=(h*8+c0)*8+kc covers rows h*512+kc*64..+63,
        //      cols c0*64..+63 ----
        const int tid = bid - 96;
        const int h  = tid >> 6;
        const int c0 = (tid >> 3) & 7;
        const int kc = tid & 7;
        const int n  = t & 63;
        const int w  = t >> 6;
        const float* gB = W1 + ((size_t)(h * 512 + kc * 64)) * 512 + c0 * 64 + n;
        unsigned short* dh = w1h + (size_t)tid * 4096;
        unsigned short* dl = w1l + (size_t)tid * 4096;
        #pragma unroll
        for (int g = 0; g < 2; ++g) {
            const int cc = w * 2 + g;
            float bv[8];
            #pragma unroll
            for (int e = 0; e < 8; ++e)
                bv[e] = gB[(size_t)(cc * 8 + e) * 512];
            union { uint4 v; unsigned short s[8]; } hv, lv;
            #pragma unroll
            for (int e = 0; e < 8; ++e) {
                const unsigned short hb = f2bf(bv[e]);
                hv.s[e] = hb; lv.s[e] = f2bf(bv[e] - bf2f(hb));
            }
            const int off = n * 64 + ((cc ^ (n & 7)) * 8);
            *(uint4*)&dh[off] = hv.v;
            *(uint4*)&dl[off] = lv.v;
        }
    }
}

// ---------------------------------------------------------------------------
// Kernel 1 (REWRITTEN): proj GEMM from pre-converted blobs. K-loop is now
// 6 uint4 global loads + 6 LDS stores + 12 ds_read_b128 + 12 MFMA per thread
// per chunk (was ~190 inst incl. conversions). Register prefetch + double
// LDS buffer, one barrier per chunk. MFMA sequence identical -> bit-identical
// ekto/eq.
// ---------------------------------------------------------------------------
__global__ __launch_bounds__(256) void proj_kernel(
    const unsigned short* __restrict__ ash, const unsigned short* __restrict__ asl,
    const unsigned short* __restrict__ w1h, const unsigned short* __restrict__ w1l,
    const float* __restrict__ b1,
    uint4* __restrict__ ekto, float* __restrict__ eq)
{
    const int bx = blockIdx.x, by = blockIdx.y;
    const int row0 = bx * 32;
    const bool isK = row0 < 2048;
    const int h = isK ? 0 : 1;
    const int col0 = by * 64;

    __shared__ __align__(16) unsigned short As_h[2][2048];
    __shared__ __align__(16) unsigned short As_l[2][2048];
    __shared__ __align__(16) unsigned short Bs_h[2][4096];
    __shared__ __align__(16) unsigned short Bs_l[2][4096];

    const int t    = threadIdx.x;
    const int wave = t >> 6;
    const int lane = t & 63;
    const int wm = (wave & 1) * 16;
    const int wn = (wave >> 1) * 32;
    const int quad = lane >> 4, fr = lane & 15;

    f32x4 acc[2] = {};

    const uint4* ah = (const uint4*)ash + (size_t)bx * 8 * 256;
    const uint4* al = (const uint4*)asl + (size_t)bx * 8 * 256;
    const int tidB = (h * 8 + by) * 8;
    const uint4* bh = (const uint4*)w1h + (size_t)tidB * 512;
    const uint4* bl = (const uint4*)w1l + (size_t)tidB * 512;

    uint4 rAh = ah[t], rAl = al[t];
    uint4 rBh0 = bh[t], rBh1 = bh[256 + t];
    uint4 rBl0 = bl[t], rBl1 = bl[256 + t];

    for (int kc = 0; kc < 8; ++kc) {
        const int cur = kc & 1;
        *(uint4*)&As_h[cur][t * 8] = rAh;
        *(uint4*)&As_l[cur][t * 8] = rAl;
        *(uint4*)&Bs_h[cur][t * 8] = rBh0;
        *(uint4*)&Bs_h[cur][2048 + t * 8] = rBh1;
        *(uint4*)&Bs_l[cur][t * 8] = rBl0;
        *(uint4*)&Bs_l[cur][2048 + t * 8] = rBl1;
        __syncthreads();
        if (kc < 7) {
            const int nx = kc + 1;
            rAh = ah[nx * 256 + t];  rAl = al[nx * 256 + t];
            rBh0 = bh[nx * 512 + t]; rBh1 = bh[nx * 512 + 256 + t];
            rBl0 = bl[nx * 512 + t]; rBl1 = bl[nx * 512 + 256 + t];
        }
        #pragma unroll
        for (int ks = 0; ks < 2; ++ks) {
            const int cchunk = ks * 4 + quad;
            const int m = wm + fr;
            const bf16x8 afh = *(const bf16x8*)&As_h[cur][m * 64 + ((cchunk ^ (m & 7)) * 8)];
            const bf16x8 afl = *(const bf16x8*)&As_l[cur][m * 64 + ((cchunk ^ (m & 7)) * 8)];
            bf16x8 bfh[2], bfl[2];
            #pragma unroll
            for (int nt = 0; nt < 2; ++nt) {
                const int n = wn + nt * 16 + fr;
                bfh[nt] = *(const bf16x8*)&Bs_h[cur][n * 64 + ((cchunk ^ (n & 7)) * 8)];
                bfl[nt] = *(const bf16x8*)&Bs_l[cur][n * 64 + ((cchunk ^ (n & 7)) * 8)];
            }
            #pragma unroll
            for (int nt = 0; nt < 2; ++nt) {
                acc[nt] = __builtin_amdgcn_mfma_f32_16x16x32_bf16(afh, bfh[nt], acc[nt], 0, 0, 0);
                acc[nt] = __builtin_amdgcn_mfma_f32_16x16x32_bf16(afh, bfl[nt], acc[nt], 0, 0, 0);
                acc[nt] = __builtin_amdgcn_mfma_f32_16x16x32_bf16(afl, bfh[nt], acc[nt], 0, 0, 0);
            }
        }
    }

    #pragma unroll
    for (int nt = 0; nt < 2; ++nt) {
        const int colg = col0 + wn + nt * 16 + fr;
        const float b1v = b1[colg];
        #pragma unroll
        for (int i = 0; i < 4; ++i) {
            const int rowg = row0 + wm + quad * 4 + i;
            const float v = acc[nt][i];
            if (isK) {
                const float e = fexp2((v + b1v) * C2L2E);
                const float ep = __shfl_xor(e, 1, 64);
                unsigned pk = ((fr & 1) == 0) ? packbf(e, ep) : packbf(ep, e);
                unsigned pk2 = __shfl_xor(pk, 2, 64);
                if (fr & 2) { unsigned tmp = pk; pk = pk2; pk2 = tmp; }
                const unsigned px  = __shfl_xor(pk, 4, 64);
                const unsigned px2 = __shfl_xor(pk2, 4, 64);
                if ((fr & 7) == 0) {
                    const int kidx = rowg >> 3;
                    const int bb   = rowg & 7;
                    const int ho   = colg >> 3;
                    ekto[((size_t)bb * 64 + ho) * 256 + kidx] =
                        make_uint4(pk, pk2, px, px2);
                }
            } else {
                eq[(size_t)(rowg - 2048) * 512 + colg] = fexp2(v * C2L2E);
            }
        }
    }
}

// ---------------------------------------------------------------------------
// Kernel 2: fused score + softmax + antvec. R19: 4 q per block (256 blocks,
// exactly 1/CU, no tail; b=bid&7 stays XCD-bijective). Halves ekto/ckp
// re-read traffic (256->128 MB). Per-term math order identical to R18.
// ---------------------------------------------------------------------------
__global__ __launch_bounds__(512, 2) void scoreav_kernel(
    const uint4* __restrict__ ekto, const float* __restrict__ eq,
    const float* __restrict__ W2, const float* __restrict__ b2,
    const int* __restrict__ mask, const unsigned int* __restrict__ ckp,
    float* __restrict__ prob_out, float* __restrict__ out_ant)
{
    const int t    = threadIdx.x;
    const int lane = t & 63;
    const int wave = __builtin_amdgcn_readfirstlane(t >> 6);
    const int hu   = __builtin_amdgcn_readfirstlane(t >> 8);
    const int kk   = t & 255;
    const int bid  = blockIdx.x;
    const int b    = bid & 7;
    const int q0   = (bid >> 3) * 4;

    __shared__ __align__(16) f32x2 eqpA[512];   // 4 KB (q0,q0+1)
    __shared__ __align__(16) f32x2 eqpB[512];   // 4 KB (q0+2,q0+3)
    __shared__ __align__(16) f32x2 rpA[512];    // 4 KB
    __shared__ __align__(16) f32x2 rpB[512];    // 4 KB
    __shared__ float ps[4][256];                // 4 KB
    __shared__ __align__(8) f32x2 psA[256];     // 2 KB
    __shared__ __align__(8) f32x2 psB[256];     // 2 KB

    {
        const float* e0 = eq + ((size_t)q0 * 8 + b) * 512;
        f32x2 va; va.x = e0[t];        va.y = e0[4096 + t];
        f32x2 vb; vb.x = e0[8192 + t]; vb.y = e0[12288 + t];
        eqpA[t] = va; eqpB[t] = vb;
    }

    const float4 wA = *(const float4*)&W2[lane * 4];
    const float4 wB = *(const float4*)&W2[256 + lane * 4];
    float s2 = wA.x + wA.y + wA.z + wA.w + wB.x + wB.y + wB.z + wB.w;
    #pragma unroll
    for (int m = 32; m; m >>= 1) s2 += __shfl_xor(s2, m, 64);
    const float base = s2 + b2[0];
    __syncthreads();

    // ---- score ----
    const uint4* __restrict__ ekb = ekto + (size_t)b * 64 * 256 + kk;
    const f32x2 one2 = {1.0f, 1.0f};
    f32x2 raA = {0.f, 0.f}, rbA = {0.f, 0.f};
    f32x2 raB = {0.f, 0.f}, rbB = {0.f, 0.f};

    uint4 LA0, LA1, LA2, LA3, LB0, LB1, LB2, LB3;

#define PREF(D, G) \
    D##0 = ekb[(size_t)(hu * 32 + (G) * 4 + 0) * 256]; \
    D##1 = ekb[(size_t)(hu * 32 + (G) * 4 + 1) * 256]; \
    D##2 = ekb[(size_t)(hu * 32 + (G) * 4 + 2) * 256]; \
    D##3 = ekb[(size_t)(hu * 32 + (G) * 4 + 3) * 256];

#define RAT(eka, ekb_, ekc, ekd, E01, E23, wx, wy, wz, ww, ACC) { \
    const f32x2 a0 = fma2((f32x2){eka, eka}, (f32x2){E01.x, E01.y}, one2); \
    const f32x2 a1 = fma2((f32x2){ekb_, ekb_}, (f32x2){E01.z, E01.w}, one2); \
    const f32x2 a2 = fma2((f32x2){ekc, ekc}, (f32x2){E23.x, E23.y}, one2); \
    const f32x2 a3 = fma2((f32x2){ekd, ekd}, (f32x2){E23.z, E23.w}, one2); \
    const f32x2 d01 = a0 * a1, d23 = a2 * a3; \
    const f32x2 n01 = fma2((f32x2){wx, wx}, a1, (f32x2){wy, wy} * a0); \
    const f32x2 n23 = fma2((f32x2){wz, wz}, a3, (f32x2){ww, ww} * a2); \
    const f32x2 N = fma2(n01, d23, n23 * d01); \
    const f32x2 D = d01 * d23; \
    const f32x2 R = {frcp(D.x), frcp(D.y)}; \
    ACC = fma2(N, R, ACC); \
}

#define JBODY(U, G, J) { \
    const int hw = (hu * 32 + (G) * 4 + (J)) * 8; \
    const float ek0 = lo16(U.x), ek1 = hi16(U.x); \
    const float ek2 = lo16(U.y), ek3 = hi16(U.y); \
    const float ek4 = lo16(U.z), ek5 = hi16(U.z); \
    const float ek6 = lo16(U.w), ek7 = hi16(U.w); \
    const f32x4v EA01 = *(const f32x4v*)&eqpA[hw]; \
    const f32x4v EA23 = *(const f32x4v*)&eqpA[hw + 2]; \
    const f32x4v EA45 = *(const f32x4v*)&eqpA[hw + 4]; \
    const f32x4v EA67 = *(const f32x4v*)&eqpA[hw + 6]; \
    const f32x4v EB01 = *(const f32x4v*)&eqpB[hw]; \
    const f32x4v EB23 = *(const f32x4v*)&eqpB[hw + 2]; \
    const f32x4v EB45 = *(const f32x4v*)&eqpB[hw + 4]; \
    const f32x4v EB67 = *(const f32x4v*)&eqpB[hw + 6]; \
    const float w0 = W2[hw + 0], w1 = W2[hw + 1]; \
    const float w2v = W2[hw + 2], w3 = W2[hw + 3]; \
    const float w4 = W2[hw + 4], w5 = W2[hw + 5]; \
    const float w6 = W2[hw + 6], w7 = W2[hw + 7]; \
    RAT(ek0, ek1, ek2, ek3, EA01, EA23, w0, w1, w2v, w3, raA) \
    RAT(ek4, ek5, ek6, ek7, EA45, EA67, w4, w5, w6, w7, rbA) \
    RAT(ek0, ek1, ek2, ek3, EB01, EB23, w0, w1, w2v, w3, raB) \
    RAT(ek4, ek5, ek6, ek7, EB45, EB67, w4, w5, w6, w7, rbB) \
}

#define GROUP(D, G) JBODY(D##0, G, 0) JBODY(D##1, G, 1) JBODY(D##2, G, 2) JBODY(D##3, G, 3)

    PREF(LA, 0)
    PREF(LB, 1) GROUP(LA, 0)
    PREF(LA, 2) GROUP(LB, 1)
    PREF(LB, 3) GROUP(LA, 2)
    PREF(LA, 4) GROUP(LB, 3)
    PREF(LB, 5) GROUP(LA, 4)
    PREF(LA, 6) GROUP(LB, 5)
    PREF(LB, 7) GROUP(LA, 6)
                GROUP(LB, 7)

#undef GROUP
#undef JBODY
#undef RAT
#undef PREF

    rpA[t] = raA + rbA;
    rpB[t] = raB + rbB;
    __syncthreads();

    if (t < 256) {
        const int msk = mask[t * 8 + b];
        const f32x2 rsA = rpA[t] + rpA[t + 256];
        const f32x2 rsB = rpB[t] + rpB[t + 256];
        float s0 = base - 2.0f * rsA.x;
        float s1 = base - 2.0f * rsA.y;
        float s2_ = base - 2.0f * rsB.x;
        float s3 = base - 2.0f * rsB.y;
        if (msk) { s0 = -INFINITY; s1 = -INFINITY; s2_ = -INFINITY; s3 = -INFINITY; }
        ps[0][t] = s0; ps[1][t] = s1; ps[2][t] = s2_; ps[3][t] = s3;
    }
    __syncthreads();

    // ---- softmax: waves 0..3 (wave w -> q0+w) ----
    if (wave < 4) {
        float4 sv = *(const float4*)&ps[wave][lane * 4];
        float m = fmaxf(fmaxf(sv.x, sv.y), fmaxf(sv.z, sv.w));
        #pragma unroll
        for (int d = 32; d; d >>= 1) m = fmaxf(m, __shfl_xor(m, d, 64));
        float4 pv;
        pv.x = fexp2((sv.x - m) * L2E);
        pv.y = fexp2((sv.y - m) * L2E);
        pv.z = fexp2((sv.z - m) * L2E);
        pv.w = fexp2((sv.w - m) * L2E);
        float sum = pv.x + pv.y + pv.z + pv.w;
        #pragma unroll
        for (int d = 32; d; d >>= 1) sum += __shfl_xor(sum, d, 64);
        const float inv = frcp(sum);
        pv.x *= inv; pv.y *= inv; pv.z *= inv; pv.w *= inv;
        float* pf = (wave < 2) ? (float*)psA : (float*)psB;
        const int c = wave & 1;
        pf[(lane * 4 + 0) * 2 + c] = pv.x;
        pf[(lane * 4 + 1) * 2 + c] = pv.y;
        pf[(lane * 4 + 2) * 2 + c] = pv.z;
        pf[(lane * 4 + 3) * 2 + c] = pv.w;
        const int qb_idx = (q0 + wave) * 8 + b;
        const int kbase = lane * 4;
        prob_out[(size_t)(kbase + 0) * 1024 + qb_idx] = pv.x;
        prob_out[(size_t)(kbase + 1) * 1024 + qb_idx] = pv.y;
        prob_out[(size_t)(kbase + 2) * 1024 + qb_idx] = pv.z;
        prob_out[(size_t)(kbase + 3) * 1024 + qb_idx] = pv.w;
    }
    __syncthreads();

    // ---- antvec: wave -> 64 h; 4 q via two f32x2 accumulator sets ----
    {
        const int kq = lane >> 3;
        const int hq = lane & 7;
        const int pbase = wave * 32 + hq * 4;
        const unsigned int* __restrict__ ckb = ckp + (size_t)b * 256 * 256;
        f32x2 aA0 = {}, aA1 = {}, aA2 = {}, aA3 = {}, aA4 = {}, aA5 = {}, aA6 = {}, aA7 = {};
        f32x2 aB0 = {}, aB1 = {}, aB2 = {}, aB3 = {}, aB4 = {}, aB5 = {}, aB6 = {}, aB7 = {};
        #pragma unroll 8
        for (int ki = 0; ki < 32; ++ki) {
            const int k = ki * 8 + kq;
            const uint4 U = *(const uint4*)&ckb[(size_t)k * 256 + pbase];
            const float c0 = lo16(U.x), c1 = hi16(U.x);
            const float c2 = lo16(U.y), c3 = hi16(U.y);
            const float c4 = lo16(U.z), c5 = hi16(U.z);
            const float c6 = lo16(U.w), c7 = hi16(U.w);
            const f32x2 pA = psA[k];
            const f32x2 pB = psB[k];
            aA0 = fma2(pA, (f32x2){c0, c0}, aA0); aB0 = fma2(pB, (f32x2){c0, c0}, aB0);
            aA1 = fma2(pA, (f32x2){c1, c1}, aA1); aB1 = fma2(pB, (f32x2){c1, c1}, aB1);
            aA2 = fma2(pA, (f32x2){c2, c2}, aA2); aB2 = fma2(pB, (f32x2){c2, c2}, aB2);
            aA3 = fma2(pA, (f32x2){c3, c3}, aA3); aB3 = fma2(pB, (f32x2){c3, c3}, aB3);
            aA4 = fma2(pA, (f32x2){c4, c4}, aA4); aB4 = fma2(pB, (f32x2){c4, c4}, aB4);
            aA5 = fma2(pA, (f32x2){c5, c5}, aA5); aB5 = fma2(pB, (f32x2){c5, c5}, aB5);
            aA6 = fma2(pA, (f32x2){c6, c6}, aA6); aB6 = fma2(pB, (f32x2){c6, c6}, aB6);
            aA7 = fma2(pA, (f32x2){c7, c7}, aA7); aB7 = fma2(pB, (f32x2){c7, c7}, aB7);
        }
#define RED(v) { v.x += __shfl_xor(v.x, d, 64); v.y += __shfl_xor(v.y, d, 64); }
        #pragma unroll
        for (int d = 8; d <= 32; d <<= 1) {
            RED(aA0) RED(aA1) RED(aA2) RED(aA3) RED(aA4) RED(aA5) RED(aA6) RED(aA7)
            RED(aB0) RED(aB1) RED(aB2) RED(aB3) RED(aB4) RED(aB5) RED(aB6) RED(aB7)
        }
#undef RED
        if (lane < 8) {
            const int h0 = wave * 64 + hq * 8;
            float* o0 = &out_ant[((size_t)(q0 + 0) * 8 + b) * 512 + h0];
            float* o1 = &out_ant[((size_t)(q0 + 1) * 8 + b) * 512 + h0];
            float* o2 = &out_ant[((size_t)(q0 + 2) * 8 + b) * 512 + h0];
            float* o3 = &out_ant[((size_t)(q0 + 3) * 8 + b) * 512 + h0];
            o0[0] = aA0.x; o0[1] = aA1.x; o0[2] = aA2.x; o0[3] = aA3.x;
            o0[4] = aA4.x; o0[5] = aA5.x; o0[6] = aA6.x; o0[7] = aA7.x;
            o1[0] = aA0.y; o1[1] = aA1.y; o1[2] = aA2.y; o1[3] = aA3.y;
            o1[4] = aA4.y; o1[5] = aA5.y; o1[6] = aA6.y; o1[7] = aA7.y;
            o2[0] = aB0.x; o2[1] = aB1.x; o2[2] = aB2.x; o2[3] = aB3.x;
            o2[4] = aB4.x; o2[5] = aB5.x; o2[6] = aB6.x; o2[7] = aB7.x;
            o3[0] = aB0.y; o3[1] = aB1.y; o3[2] = aB2.y; o3[3] = aB3.y;
            o3[4] = aB4.y; o3[5] = aB5.y; o3[6] = aB6.y; o3[7] = aB7.y;
        }
    }
}

// ---------------------------------------------------------------------------
extern "C" void kernel_launch(void* const* d_in, const int* in_sizes, int n_in,
                              void* d_out, int out_size, void* d_ws, size_t ws_size,
                              hipStream_t stream)
{
    const float* qry  = (const float*)d_in[0];
    const float* ckey = (const float*)d_in[1];
    const int*   mask = (const int*)d_in[2];
    const float* W1   = (const float*)d_in[3];
    const float* b1   = (const float*)d_in[4];
    const float* W2   = (const float*)d_in[5];
    const float* b2   = (const float*)d_in[6];

    float* out_ant  = (float*)d_out;
    float* out_prob = (float*)d_out + T_Q * BB * NHID;

    float* ws = (float*)d_ws;
    uint4* ws_ekto = (uint4*)ws;                                   // 2 MB
    float* ws_eq   = ws + 524288;                                  // 2 MB
    unsigned int* ws_ckp = (unsigned int*)(ws + 1048576);          // 2 MB
    unsigned short* ws_w1h = (unsigned short*)(ws + 1572864);      // 1 MB
    unsigned short* ws_w1l = (unsigned short*)(ws + 1835008);      // 1 MB
    unsigned short* ws_ash = (unsigned short*)(ws + 2097152);      // 3 MB
    unsigned short* ws_asl = (unsigned short*)(ws + 2883584);      // 3 MB

    prep_kernel<<<dim3(224), 256, 0, stream>>>(qry, ckey, W1,
                                               ws_ash, ws_asl, ws_w1h, ws_w1l, ws_ckp);
    proj_kernel<<<dim3(96, 8), 256, 0, stream>>>(ws_ash, ws_asl, ws_w1h, ws_w1l,
                                                 b1, ws_ekto, ws_eq);
    scoreav_kernel<<<dim3(256), 512, 0, stream>>>(ws_ekto, ws_eq, W2, b2, mask, ws_ckp,
                                                  out_prob, out_ant);
}

// Round 5
// 110.257 us; speedup vs baseline: 1.0408x; 1.0408x over previous
//
#include <hip/hip_runtime.h>
#include <math.h>

#define NHID 512
#define T_K  256
#define T_Q  128
#define BB   8

// tanh(x) = 1 - 2/(exp2(C*x)+1), C = 2*log2(e)
constexpr float C2L2E = 2.8853900817779268f;
constexpr float L2E   = 1.4426950408889634f;

__device__ __forceinline__ float fexp2(float x) { return __builtin_amdgcn_exp2f(x); }
__device__ __forceinline__ float frcp(float x)  { return __builtin_amdgcn_rcpf(x); }

typedef __attribute__((ext_vector_type(8))) short bf16x8;
typedef __attribute__((ext_vector_type(4))) float f32x4;
typedef __attribute__((ext_vector_type(2))) float f32x2;
typedef __attribute__((ext_vector_type(4))) float f32x4v;

__device__ __forceinline__ f32x2 fma2(f32x2 a, f32x2 b, f32x2 c) {
    return __builtin_elementwise_fma(a, b, c);
}

__device__ __forceinline__ unsigned short f2bf(float x) {
    unsigned u = __builtin_bit_cast(unsigned, x);
    unsigned r = (u + 0x7FFFu + ((u >> 16) & 1u)) >> 16;
    return (unsigned short)r;
}
__device__ __forceinline__ float bf2f(unsigned short h) {
    unsigned u = ((unsigned)h) << 16;
    return __builtin_bit_cast(float, u);
}
__device__ __forceinline__ unsigned packbf(float a, float b) {
    return (unsigned)f2bf(a) | ((unsigned)f2bf(b) << 16);
}
__device__ __forceinline__ float lo16(unsigned u) {
    return __builtin_bit_cast(float, u << 16);
}
__device__ __forceinline__ float hi16(unsigned u) {
    return __builtin_bit_cast(float, u & 0xFFFF0000u);
}

// ---------------------------------------------------------------------------
// Kernel 1: proj GEMM, in-kernel W1 transpose/split, free ckp emission.
// (Reverted to the R2-measured best: in-proj conversion, no prep kernel.)
// ---------------------------------------------------------------------------
__global__ __launch_bounds__(256) void proj_kernel(
    const float* __restrict__ qry, const float* __restrict__ ckey,
    const float* __restrict__ W1, const float* __restrict__ b1,
    uint4* __restrict__ ekto, float* __restrict__ eq,
    unsigned int* __restrict__ ckp)
{
    const int row0 = blockIdx.x * 32;
    const int col0 = blockIdx.y * 64;
    const bool isK = row0 < 2048;
    const int bhalf = isK ? 0 : 512;

    __shared__ __align__(16) unsigned short As_h[32 * 64];
    __shared__ __align__(16) unsigned short As_l[32 * 64];
    __shared__ __align__(16) unsigned short Bs_h[64 * 64];
    __shared__ __align__(16) unsigned short Bs_l[64 * 64];

    const int t    = threadIdx.x;
    const int wave = t >> 6;
    const int lane = t & 63;
    const int wm = (wave & 1) * 16;
    const int wn = (wave >> 1) * 32;

    f32x4 acc[2] = {};

    const int srA = t >> 3;
    const int scA = (t & 7) * 8;
    const float* gA = (isK ? ckey + (size_t)(row0 + srA) * 512
                           : qry  + (size_t)(row0 - 2048 + srA) * 512) + scA;
    const int swA = ((scA >> 3) ^ (srA & 7)) * 8;
    const bool emit_ckp = isK && (col0 == 0);
    const int rowA = row0 + srA;
    unsigned int* ckp_dst = emit_ckp
        ? ckp + ((size_t)(rowA & 7) * 256 + (rowA >> 3)) * 256
        : nullptr;

    const int nB = t & 63;
    const int kgB = wave * 16;
    const float* gB = W1 + (size_t)(bhalf + kgB) * 512 + col0 + nB;
    const int caB = wave * 2;
    const int swB0 = nB * 64 + (((caB + 0) ^ (nB & 7)) * 8);
    const int swB1 = nB * 64 + (((caB + 1) ^ (nB & 7)) * 8);

    const int quad = lane >> 4, fr = lane & 15;

    float4 pa0 = *(const float4*)&gA[0];
    float4 pa1 = *(const float4*)&gA[4];
    float bv[16];
    #pragma unroll
    for (int kk = 0; kk < 16; ++kk)
        bv[kk] = gB[(size_t)kk * 512];

    for (int k0 = 0; k0 < 512; k0 += 64) {
        float fa[8];
        *(float4*)&fa[0] = pa0; *(float4*)&fa[4] = pa1;
        union { uint4 v; unsigned short s[8]; } hA, lA, bh0, bh1, bl0, bl1;
        #pragma unroll
        for (int e = 0; e < 8; ++e) {
            const unsigned short hb = f2bf(fa[e]);
            hA.s[e] = hb; lA.s[e] = f2bf(fa[e] - bf2f(hb));
        }
        #pragma unroll
        for (int e = 0; e < 8; ++e) {
            const unsigned short hb = f2bf(bv[e]);
            bh0.s[e] = hb; bl0.s[e] = f2bf(bv[e] - bf2f(hb));
        }
        #pragma unroll
        for (int e = 0; e < 8; ++e) {
            const unsigned short hb = f2bf(bv[8 + e]);
            bh1.s[e] = hb; bl1.s[e] = f2bf(bv[8 + e] - bf2f(hb));
        }
        if (emit_ckp)
            *(uint4*)&ckp_dst[(k0 + scA) >> 1] = hA.v;

        __syncthreads();
        *(uint4*)&As_h[srA * 64 + swA] = hA.v;
        *(uint4*)&As_l[srA * 64 + swA] = lA.v;
        *(uint4*)&Bs_h[swB0] = bh0.v;  *(uint4*)&Bs_h[swB1] = bh1.v;
        *(uint4*)&Bs_l[swB0] = bl0.v;  *(uint4*)&Bs_l[swB1] = bl1.v;
        __syncthreads();

        if (k0 + 64 < 512) {
            pa0 = *(const float4*)&gA[k0 + 64];
            pa1 = *(const float4*)&gA[k0 + 68];
            #pragma unroll
            for (int kk = 0; kk < 16; ++kk)
                bv[kk] = gB[(size_t)(k0 + 64 + kk) * 512];
        }

        #pragma unroll
        for (int ks = 0; ks < 2; ++ks) {
            const int cchunk = ks * 4 + quad;
            const int m = wm + fr;
            const bf16x8 afh = *(const bf16x8*)&As_h[m * 64 + ((cchunk ^ (m & 7)) * 8)];
            const bf16x8 afl = *(const bf16x8*)&As_l[m * 64 + ((cchunk ^ (m & 7)) * 8)];
            bf16x8 bfh[2], bfl[2];
            #pragma unroll
            for (int nt = 0; nt < 2; ++nt) {
                const int n = wn + nt * 16 + fr;
                bfh[nt] = *(const bf16x8*)&Bs_h[n * 64 + ((cchunk ^ (n & 7)) * 8)];
                bfl[nt] = *(const bf16x8*)&Bs_l[n * 64 + ((cchunk ^ (n & 7)) * 8)];
            }
            #pragma unroll
            for (int nt = 0; nt < 2; ++nt) {
                acc[nt] = __builtin_amdgcn_mfma_f32_16x16x32_bf16(afh, bfh[nt], acc[nt], 0, 0, 0);
                acc[nt] = __builtin_amdgcn_mfma_f32_16x16x32_bf16(afh, bfl[nt], acc[nt], 0, 0, 0);
                acc[nt] = __builtin_amdgcn_mfma_f32_16x16x32_bf16(afl, bfh[nt], acc[nt], 0, 0, 0);
            }
        }
    }

    #pragma unroll
    for (int nt = 0; nt < 2; ++nt) {
        const int colg = col0 + wn + nt * 16 + fr;
        const float b1v = b1[colg];
        #pragma unroll
        for (int i = 0; i < 4; ++i) {
            const int rowg = row0 + wm + quad * 4 + i;
            const float v = acc[nt][i];
            if (isK) {
                const float e = fexp2((v + b1v) * C2L2E);
                const float ep = __shfl_xor(e, 1, 64);
                unsigned pk = ((fr & 1) == 0) ? packbf(e, ep) : packbf(ep, e);
                unsigned pk2 = __shfl_xor(pk, 2, 64);
                if (fr & 2) { unsigned tmp = pk; pk = pk2; pk2 = tmp; }
                const unsigned px  = __shfl_xor(pk, 4, 64);
                const unsigned px2 = __shfl_xor(pk2, 4, 64);
                if ((fr & 7) == 0) {
                    const int kidx = rowg >> 3;
                    const int bb   = rowg & 7;
                    const int ho   = colg >> 3;
                    ekto[((size_t)bb * 64 + ho) * 256 + kidx] =
                        make_uint4(pk, pk2, px, px2);
                }
            } else {
                eq[(size_t)(rowg - 2048) * 512 + colg] = fexp2(v * C2L2E);
            }
        }
    }
}

// ---------------------------------------------------------------------------
// Kernel 2: fused score + softmax + antvec. (Reverted to the R2-measured
// best: q-paired f32x2 math, W2 via scalar loads, grid (64,8), 2 q/block.)
// ---------------------------------------------------------------------------
__global__ __launch_bounds__(512, 4) void scoreav_kernel(
    const uint4* __restrict__ ekto, const float* __restrict__ eq,
    const float* __restrict__ W2, const float* __restrict__ b2,
    const int* __restrict__ mask, const unsigned int* __restrict__ ckp,
    float* __restrict__ prob_out, float* __restrict__ out_ant)
{
    const int t    = threadIdx.x;
    const int lane = t & 63;
    const int wave = __builtin_amdgcn_readfirstlane(t >> 6);
    const int hu   = __builtin_amdgcn_readfirstlane(t >> 8);   // wave-uniform half
    const int kk   = t & 255;
    const int q0   = blockIdx.x * 2;
    const int b    = blockIdx.y;

    __shared__ __align__(16) f32x2 eqp[512];   // 4 KB  (eq q-pairs)
    __shared__ __align__(16) f32x2 rp2[512];   // 4 KB  (partial sums, q-paired)
    __shared__ float ps[2][256];               // 2 KB  (raw scores)
    __shared__ __align__(8) f32x2 ps2[256];    // 2 KB  (normalized probs, q-paired)

    {   // stage eq pairs
        const float* eqr0 = eq + ((size_t)q0 * 8 + b) * 512;
        const float* eqr1 = eq + ((size_t)(q0 + 1) * 8 + b) * 512;
        f32x2 ep; ep.x = eqr0[t]; ep.y = eqr1[t];
        eqp[t] = ep;
    }

    const float4 wA = *(const float4*)&W2[lane * 4];
    const float4 wB = *(const float4*)&W2[256 + lane * 4];
    float s2 = wA.x + wA.y + wA.z + wA.w + wB.x + wB.y + wB.z + wB.w;
    #pragma unroll
    for (int m = 32; m; m >>= 1) s2 += __shfl_xor(s2, m, 64);
    const float base = s2 + b2[0];
    __syncthreads();

    // ---- score: thread owns (k=kk, h-octets hu*32..hu*32+31), q-paired ----
    const uint4* __restrict__ ekb = ekto + (size_t)b * 64 * 256 + kk;
    const f32x2 one2 = {1.0f, 1.0f};
    f32x2 ra = {0.f, 0.f}, rb = {0.f, 0.f};

    uint4 LA0, LA1, LA2, LA3, LB0, LB1, LB2, LB3;

#define PREF(D, G) \
    D##0 = ekb[(size_t)(hu * 32 + (G) * 4 + 0) * 256]; \
    D##1 = ekb[(size_t)(hu * 32 + (G) * 4 + 1) * 256]; \
    D##2 = ekb[(size_t)(hu * 32 + (G) * 4 + 2) * 256]; \
    D##3 = ekb[(size_t)(hu * 32 + (G) * 4 + 3) * 256];

#define JBODY(U, G, J) { \
    const int hw = (hu * 32 + (G) * 4 + (J)) * 8; \
    const float ek0 = lo16(U.x), ek1 = hi16(U.x); \
    const float ek2 = lo16(U.y), ek3 = hi16(U.y); \
    const float ek4 = lo16(U.z), ek5 = hi16(U.z); \
    const float ek6 = lo16(U.w), ek7 = hi16(U.w); \
    const f32x4v E01 = *(const f32x4v*)&eqp[hw]; \
    const f32x4v E23 = *(const f32x4v*)&eqp[hw + 2]; \
    const f32x4v E45 = *(const f32x4v*)&eqp[hw + 4]; \
    const f32x4v E67 = *(const f32x4v*)&eqp[hw + 6]; \
    const float w0 = W2[hw + 0], w1 = W2[hw + 1]; \
    const float w2v = W2[hw + 2], w3 = W2[hw + 3]; \
    const float w4 = W2[hw + 4], w5 = W2[hw + 5]; \
    const float w6 = W2[hw + 6], w7 = W2[hw + 7]; \
    { \
        const f32x2 a0 = fma2((f32x2){ek0, ek0}, (f32x2){E01.x, E01.y}, one2); \
        const f32x2 a1 = fma2((f32x2){ek1, ek1}, (f32x2){E01.z, E01.w}, one2); \
        const f32x2 a2 = fma2((f32x2){ek2, ek2}, (f32x2){E23.x, E23.y}, one2); \
        const f32x2 a3 = fma2((f32x2){ek3, ek3}, (f32x2){E23.z, E23.w}, one2); \
        const f32x2 d01 = a0 * a1, d23 = a2 * a3; \
        const f32x2 n01 = fma2((f32x2){w0, w0}, a1, (f32x2){w1, w1} * a0); \
        const f32x2 n23 = fma2((f32x2){w2v, w2v}, a3, (f32x2){w3, w3} * a2); \
        const f32x2 N = fma2(n01, d23, n23 * d01); \
        const f32x2 D = d01 * d23; \
        const f32x2 R = {frcp(D.x), frcp(D.y)}; \
        ra = fma2(N, R, ra); \
    } \
    { \
        const f32x2 a0 = fma2((f32x2){ek4, ek4}, (f32x2){E45.x, E45.y}, one2); \
        const f32x2 a1 = fma2((f32x2){ek5, ek5}, (f32x2){E45.z, E45.w}, one2); \
        const f32x2 a2 = fma2((f32x2){ek6, ek6}, (f32x2){E67.x, E67.y}, one2); \
        const f32x2 a3 = fma2((f32x2){ek7, ek7}, (f32x2){E67.z, E67.w}, one2); \
        const f32x2 d01 = a0 * a1, d23 = a2 * a3; \
        const f32x2 n01 = fma2((f32x2){w4, w4}, a1, (f32x2){w5, w5} * a0); \
        const f32x2 n23 = fma2((f32x2){w6, w6}, a3, (f32x2){w7, w7} * a2); \
        const f32x2 N = fma2(n01, d23, n23 * d01); \
        const f32x2 D = d01 * d23; \
        const f32x2 R = {frcp(D.x), frcp(D.y)}; \
        rb = fma2(N, R, rb); \
    } \
}

#define GROUP(D, G) JBODY(D##0, G, 0) JBODY(D##1, G, 1) JBODY(D##2, G, 2) JBODY(D##3, G, 3)

    PREF(LA, 0)
    PREF(LB, 1) GROUP(LA, 0)
    PREF(LA, 2) GROUP(LB, 1)
    PREF(LB, 3) GROUP(LA, 2)
    PREF(LA, 4) GROUP(LB, 3)
    PREF(LB, 5) GROUP(LA, 4)
    PREF(LA, 6) GROUP(LB, 5)
    PREF(LB, 7) GROUP(LA, 6)
                GROUP(LB, 7)

#undef GROUP
#undef JBODY
#undef PREF

    rp2[t] = ra + rb;
    __syncthreads();

    if (t < 256) {
        const int msk = mask[t * 8 + b];
        const f32x2 rsum = rp2[t] + rp2[t + 256];
        float s0 = base - 2.0f * rsum.x;
        float s1 = base - 2.0f * rsum.y;
        if (msk) { s0 = -INFINITY; s1 = -INFINITY; }
        ps[0][t] = s0;
        ps[1][t] = s1;
    }
    __syncthreads();

    // ---- softmax: waves 0,1 (wave w handles q0+w) ----
    if (wave < 2) {
        float4 sv = *(const float4*)&ps[wave][lane * 4];
        float m = fmaxf(fmaxf(sv.x, sv.y), fmaxf(sv.z, sv.w));
        #pragma unroll
        for (int d = 32; d; d >>= 1) m = fmaxf(m, __shfl_xor(m, d, 64));
        float4 pv;
        pv.x = fexp2((sv.x - m) * L2E);
        pv.y = fexp2((sv.y - m) * L2E);
        pv.z = fexp2((sv.z - m) * L2E);
        pv.w = fexp2((sv.w - m) * L2E);
        float sum = pv.x + pv.y + pv.z + pv.w;
        #pragma unroll
        for (int d = 32; d; d >>= 1) sum += __shfl_xor(sum, d, 64);
        const float inv = frcp(sum);
        pv.x *= inv; pv.y *= inv; pv.z *= inv; pv.w *= inv;
        float* p2f = (float*)ps2;
        p2f[(lane * 4 + 0) * 2 + wave] = pv.x;
        p2f[(lane * 4 + 1) * 2 + wave] = pv.y;
        p2f[(lane * 4 + 2) * 2 + wave] = pv.z;
        p2f[(lane * 4 + 3) * 2 + wave] = pv.w;
        const int qb_idx = (q0 + wave) * 8 + b;
        const int kbase = lane * 4;
        prob_out[(size_t)(kbase + 0) * 1024 + qb_idx] = pv.x;
        prob_out[(size_t)(kbase + 1) * 1024 + qb_idx] = pv.y;
        prob_out[(size_t)(kbase + 2) * 1024 + qb_idx] = pv.z;
        prob_out[(size_t)(kbase + 3) * 1024 + qb_idx] = pv.w;
    }
    __syncthreads();

    // ---- antvec: wave -> 64 h; lane = (kq = lane>>3, hq = lane&7, 8 h),
    //      q-paired accumulators ----
    {
        const int kq = lane >> 3;
        const int hq = lane & 7;
        const int pbase = wave * 32 + hq * 4;
        const unsigned int* __restrict__ ckb = ckp + (size_t)b * 256 * 256;
        f32x2 a0 = {}, a1 = {}, a2 = {}, a3 = {}, a4 = {}, a5 = {}, a6 = {}, a7 = {};
        #pragma unroll 8
        for (int ki = 0; ki < 32; ++ki) {
            const int k = ki * 8 + kq;
            const uint4 U = *(const uint4*)&ckb[(size_t)k * 256 + pbase];
            const float c0 = lo16(U.x), c1 = hi16(U.x);
            const float c2 = lo16(U.y), c3 = hi16(U.y);
            const float c4 = lo16(U.z), c5 = hi16(U.z);
            const float c6 = lo16(U.w), c7 = hi16(U.w);
            const f32x2 p = ps2[k];
            a0 = fma2(p, (f32x2){c0, c0}, a0);
            a1 = fma2(p, (f32x2){c1, c1}, a1);
            a2 = fma2(p, (f32x2){c2, c2}, a2);
            a3 = fma2(p, (f32x2){c3, c3}, a3);
            a4 = fma2(p, (f32x2){c4, c4}, a4);
            a5 = fma2(p, (f32x2){c5, c5}, a5);
            a6 = fma2(p, (f32x2){c6, c6}, a6);
            a7 = fma2(p, (f32x2){c7, c7}, a7);
        }
        #pragma unroll
        for (int d = 8; d <= 32; d <<= 1) {
            a0.x += __shfl_xor(a0.x, d, 64); a0.y += __shfl_xor(a0.y, d, 64);
            a1.x += __shfl_xor(a1.x, d, 64); a1.y += __shfl_xor(a1.y, d, 64);
            a2.x += __shfl_xor(a2.x, d, 64); a2.y += __shfl_xor(a2.y, d, 64);
            a3.x += __shfl_xor(a3.x, d, 64); a3.y += __shfl_xor(a3.y, d, 64);
            a4.x += __shfl_xor(a4.x, d, 64); a4.y += __shfl_xor(a4.y, d, 64);
            a5.x += __shfl_xor(a5.x, d, 64); a5.y += __shfl_xor(a5.y, d, 64);
            a6.x += __shfl_xor(a6.x, d, 64); a6.y += __shfl_xor(a6.y, d, 64);
            a7.x += __shfl_xor(a7.x, d, 64); a7.y += __shfl_xor(a7.y, d, 64);
        }
        if (lane < 8) {
            const int h0 = wave * 64 + hq * 8;
            float* o0 = &out_ant[((size_t)q0 * 8 + b) * 512 + h0];
            float* o1 = &out_ant[((size_t)(q0 + 1) * 8 + b) * 512 + h0];
            o0[0] = a0.x; o0[1] = a1.x; o0[2] = a2.x; o0[3] = a3.x;
            o0[4] = a4.x; o0[5] = a5.x; o0[6] = a6.x; o0[7] = a7.x;
            o1[0] = a0.y; o1[1] = a1.y; o1[2] = a2.y; o1[3] = a3.y;
            o1[4] = a4.y; o1[5] = a5.y; o1[6] = a6.y; o1[7] = a7.y;
        }
    }
}

// ---------------------------------------------------------------------------
extern "C" void kernel_launch(void* const* d_in, const int* in_sizes, int n_in,
                              void* d_out, int out_size, void* d_ws, size_t ws_size,
                              hipStream_t stream)
{
    const float* qry  = (const float*)d_in[0];
    const float* ckey = (const float*)d_in[1];
    const int*   mask = (const int*)d_in[2];
    const float* W1   = (const float*)d_in[3];
    const float* b1   = (const float*)d_in[4];
    const float* W2   = (const float*)d_in[5];
    const float* b2   = (const float*)d_in[6];

    float* out_ant  = (float*)d_out;
    float* out_prob = (float*)d_out + T_Q * BB * NHID;

    float* ws = (float*)d_ws;
    uint4* ws_ekto = (uint4*)ws;                              // [8][64][256] uint4, 2MB
    float* ws_eq  = ws + 524288;                              // [1024][512] f32, 2MB
    unsigned int* ws_ckp = (unsigned int*)(ws + 1048576);     // [8][256][256] u32, 2MB

    proj_kernel<<<dim3(96, 8), 256, 0, stream>>>(qry, ckey, W1, b1,
                                                 ws_ekto, ws_eq, ws_ckp);
    scoreav_kernel<<<dim3(64, 8), 512, 0, stream>>>(ws_ekto, ws_eq, W2, b2, mask, ws_ckp,
                                                    out_prob, out_ant);
}